// Round 9
// baseline (427.219 us; speedup 1.0000x reference)
//
#include <hip/hip_runtime.h>
#include <hip/hip_bf16.h>

#define NNODES 40000
#define NEDGES 640000
#define M2PAD  40064
#define HID    128
#define PADCAP 920064                 // >= NEDGES + 7*NNODES, multiple of 256
#define WSTRIDE_P (PADCAP + 16)       // wgtT plane stride (floats)

typedef __attribute__((ext_vector_type(8))) short bf16x8;
typedef __attribute__((ext_vector_type(4))) float f32x4;

__device__ __forceinline__ float bl(unsigned u){ return __uint_as_float(u << 16); }
__device__ __forceinline__ float bh(unsigned u){ return __uint_as_float(u & 0xFFFF0000u); }
__device__ __forceinline__ unsigned short f2b(float f){
    unsigned u = __float_as_uint(f);
    u = (u + 0x7FFFu + ((u >> 16) & 1u)) >> 16;   // round-to-nearest-even
    return (unsigned short)u;
}
__device__ __forceinline__ float fast_rcp(float x){ return __builtin_amdgcn_rcpf(x); }

__device__ __forceinline__ void g2l16(const void* g, void* l){
    __builtin_amdgcn_global_load_lds(
        (const __attribute__((address_space(1))) unsigned int*)g,
        (__attribute__((address_space(3))) unsigned int*)l, 16, 0, 0);
}

// ---------- prep: nf convert (0..4999) + transpose (5000..5255) + gru cvt (5256..5447)
//            + degree count (5448..7947) ----------
__global__ void prep_all(const float* __restrict__ node_feats,
                         const float* __restrict__ proj_W, const float* __restrict__ fc_W,
                         const float* __restrict__ gru_Wih, const int* __restrict__ dstp,
                         unsigned short* __restrict__ nf,
                         unsigned short* __restrict__ projWT, unsigned short* __restrict__ fcWT,
                         unsigned short* __restrict__ gruWb, int* __restrict__ deg){
    int b = blockIdx.x;
    if (b < 5000){
        int gid = b * 256 + threadIdx.x;     // 4 elems each
        float4 v = ((const float4*)node_feats)[gid];
        ushort4 o;
        o.x = f2b(v.x); o.y = f2b(v.y); o.z = f2b(v.z); o.w = f2b(v.w);
        ((ushort4*)nf)[gid] = o;
    } else if (b < 5256){
        int t = b - 5000;
        int c = t >> 6;                      // matrix 0..3
        int idx = (t & 63) * 256 + threadIdx.x;   // coalesced read
        const float* in   = (c == 0) ? proj_W : fc_W + (size_t)(c - 1) * 16384;
        unsigned short* o = (c == 0) ? projWT : fcWT + (size_t)(c - 1) * 16384;
        int k = idx >> 7, n = idx & 127;
        o[n * 128 + k] = f2b(in[idx]);       // scattered 2B write
    } else if (b < 5448){
        int idx = (b - 5256) * 256 + threadIdx.x;
        gruWb[idx] = f2b(gru_Wih[idx]);      // (384,128) already B^T layout
    } else {
        int e = (b - 5448) * 256 + threadIdx.x;
        atomicAdd(&deg[dstp[e]], 1);
    }
}

// ---------- CSR scan (rows padded to multiple of 8) + fill ----------
__global__ __launch_bounds__(1024) void scan_kernel(const int* __restrict__ deg,
        int* __restrict__ rowptr, int* __restrict__ cur, int Nn){
    __shared__ int wsum[17];
    __shared__ int carry;
    int t = threadIdx.x, lane = t & 63, wid = t >> 6;
    if (t == 0) carry = 0;
    __syncthreads();
    for (int base = 0; base < Nn; base += 1024){
        int idx = base + t;
        int v = (idx < Nn) ? ((deg[idx] + 7) & ~7) : 0;   // padded degree
        int x = v;
        #pragma unroll
        for (int d = 1; d < 64; d <<= 1){
            int y = __shfl_up(x, d, 64);
            if (lane >= d) x += y;
        }
        if (lane == 63) wsum[wid] = x;
        __syncthreads();
        if (wid == 0){
            int vv = (lane < 16) ? wsum[lane] : 0;
            int xx = vv;
            #pragma unroll
            for (int d = 1; d < 16; d <<= 1){
                int y = __shfl_up(xx, d, 64);
                if (lane >= d) xx += y;
            }
            if (lane < 16) wsum[lane] = xx - vv;      // exclusive
            if (lane == 15) wsum[16] = xx;            // total
        }
        __syncthreads();
        int excl = carry + wsum[wid] + (x - v);
        if (idx < Nn){ rowptr[idx] = excl; cur[idx] = excl; }
        __syncthreads();
        if (t == 0) carry += wsum[16];
        __syncthreads();
    }
    if (threadIdx.x == 0) rowptr[Nn] = carry;
}

__global__ void fill_kernel(const int* __restrict__ src, const int* __restrict__ dst,
                            int* __restrict__ cur, int* __restrict__ esrc,
                            int* __restrict__ edst){
    int e = blockIdx.x * 256 + threadIdx.x;
    int d = dst[e];
    int pos = atomicAdd(&cur[d], 1);
    esrc[pos] = src[e];
    edst[pos] = d;
}

// ---------- GEMM: C[M x Nout] = A[M x 128](bf16) * BT[Nout x 128]^T (+bias fp32) ----------
// MT=64: 4 waves, each 64 rows x 32 cols. A-fragments loaded DIRECT from global into
// registers once (reused over all B); only B staged in LDS. Optional fused el/er.
template<int MT>
__global__ __launch_bounds__(256) void gemm_t(
        const unsigned short* __restrict__ A, const unsigned short* __restrict__ BT,
        const float* __restrict__ bias, void* __restrict__ C,
        int Mreal, int ldc, int outF32,
        const float* __restrict__ al, const float* __restrict__ ar,
        float* __restrict__ elp, float* __restrict__ erp)
{
    __shared__ unsigned char ldsB[32768];
    int w = threadIdx.x >> 6, lane = threadIdx.x & 63;
    int rsub = lane >> 4, c16 = lane & 15;
    long baseM = (long)blockIdx.x * MT;
    long baseN = (long)blockIdx.y * 128;
    int q = lane >> 4, cl = lane & 15;

    // stage B (128 rows x 256B) via global_load_lds, swizzled chunks
    #pragma unroll
    for (int i = 0; i < 8; i++){
        int chunk = w * 8 + i;
        int r = chunk * 4 + rsub;
        int cg = c16 ^ (r & 15);
        long br = baseN + r;
        g2l16((const unsigned char*)BT + br * 256 + cg * 16, ldsB + chunk * 1024);
    }

    // A-fragments direct from global: row*256 + kc*64 + q*16, all 4x4 up-front
    constexpr int MI = 4;
    constexpr int NI = 2;
    const unsigned char* Ab = (const unsigned char*)A;
    bf16x8 av[MI][4];
    #pragma unroll
    for (int mi = 0; mi < MI; mi++){
        long gm = baseM + mi * 16 + cl;
        if (gm >= Mreal) gm = Mreal - 1;
        const unsigned char* rp = Ab + gm * 256 + q * 16;
        #pragma unroll
        for (int kc = 0; kc < 4; kc++)
            av[mi][kc] = *(const bf16x8*)(rp + kc * 64);
    }
    __syncthreads();

    int no = w * 32;
    f32x4 acc[MI][NI];
    #pragma unroll
    for (int i = 0; i < MI; i++)
        #pragma unroll
        for (int j = 0; j < NI; j++) acc[i][j] = (f32x4){0.f, 0.f, 0.f, 0.f};

    #pragma unroll
    for (int kc = 0; kc < 4; kc++){
        bf16x8 bv[NI];
        #pragma unroll
        for (int ni = 0; ni < NI; ni++){
            int row = no + ni * 16 + cl;
            int cs = (kc * 4 + q) ^ (row & 15);
            bv[ni] = *(const bf16x8*)(ldsB + row * 256 + cs * 16);
        }
        #pragma unroll
        for (int mi = 0; mi < MI; mi++)
            #pragma unroll
            for (int ni = 0; ni < NI; ni++)
                acc[mi][ni] = __builtin_amdgcn_mfma_f32_16x16x32_bf16(av[mi][kc], bv[ni], acc[mi][ni], 0, 0, 0);
    }

    // epilogue: C/D layout col=lane&15, row=(lane>>4)*4+reg
    #pragma unroll
    for (int mi = 0; mi < MI; mi++){
        #pragma unroll
        for (int ni = 0; ni < NI; ni++){
            int gn = (int)baseN + no + ni * 16 + cl;
            float bvf = bias ? bias[gn] : 0.f;
            long gm0 = baseM + mi * 16 + q * 4;
            #pragma unroll
            for (int reg = 0; reg < 4; reg++){
                float v = acc[mi][ni][reg] + bvf;
                long gm = gm0 + reg;
                if (gm < Mreal){
                    if (outF32) ((float*)C)[gm * ldc + gn] = v;
                    else ((unsigned short*)C)[gm * ldc + gn] = f2b(v);
                }
            }
        }
    }

    // fused el/er: wave w == head w (cols w*32..w*32+31). 16-lane xor reduction over cl.
    if (al){
        float al_lo = al[no + cl], al_hi = al[no + 16 + cl];
        float ar_lo = ar[no + cl], ar_hi = ar[no + 16 + cl];
        #pragma unroll
        for (int mi = 0; mi < MI; mi++){
            #pragma unroll
            for (int reg = 0; reg < 4; reg++){
                float pl = acc[mi][0][reg] * al_lo + acc[mi][1][reg] * al_hi;
                float pr = acc[mi][0][reg] * ar_lo + acc[mi][1][reg] * ar_hi;
                #pragma unroll
                for (int msk = 8; msk; msk >>= 1){
                    pl += __shfl_xor(pl, msk, 64);
                    pr += __shfl_xor(pr, msk, 64);
                }
                long gm = baseM + mi * 16 + q * 4 + reg;
                if (cl == 0 && gm < Mreal){
                    elp[gm * 4 + w] = pl;
                    erp[gm * 4 + w] = pr;
                }
            }
        }
    }
}

// ---------- fused GRU: A-frags in registers (invariant over 3 B-chunks), B in LDS ----------
__global__ __launch_bounds__(256) void gru_fused(
        const unsigned short* __restrict__ A, const unsigned short* __restrict__ BT,
        const float* __restrict__ bih, const float* __restrict__ bhh,
        void* __restrict__ out, int Mreal, int outF32)
{
    __shared__ unsigned char ldsB[32768];
    int w = threadIdx.x >> 6, lane = threadIdx.x & 63;
    int rsub = lane >> 4, c16 = lane & 15;
    long baseM = (long)blockIdx.x * 64;
    int no = w * 32;
    int q = lane >> 4, cl = lane & 15;

    // A-fragments once
    const unsigned char* Ab = (const unsigned char*)A;
    bf16x8 av[4][4];
    #pragma unroll
    for (int mi = 0; mi < 4; mi++){
        long gm = baseM + mi * 16 + cl;
        if (gm >= Mreal) gm = Mreal - 1;
        const unsigned char* rp = Ab + gm * 256 + q * 16;
        #pragma unroll
        for (int kc = 0; kc < 4; kc++)
            av[mi][kc] = *(const bf16x8*)(rp + kc * 64);
    }

    f32x4 acc[3][4][2];
    #pragma unroll
    for (int c = 0; c < 3; c++)
        #pragma unroll
        for (int i = 0; i < 4; i++)
            #pragma unroll
            for (int j = 0; j < 2; j++) acc[c][i][j] = (f32x4){0.f, 0.f, 0.f, 0.f};

    for (int c = 0; c < 3; c++){
        if (c) __syncthreads();
        #pragma unroll
        for (int i = 0; i < 8; i++){
            int chunk = w * 8 + i;
            int r = chunk * 4 + rsub;
            int cg = c16 ^ (r & 15);
            long br = c * 128 + r;
            g2l16((const unsigned char*)BT + br * 256 + cg * 16, ldsB + chunk * 1024);
        }
        __syncthreads();
        #pragma unroll
        for (int kc = 0; kc < 4; kc++){
            bf16x8 bv[2];
            #pragma unroll
            for (int ni = 0; ni < 2; ni++){
                int row = no + ni * 16 + cl;
                int cs = (kc * 4 + q) ^ (row & 15);
                bv[ni] = *(const bf16x8*)(ldsB + row * 256 + cs * 16);
            }
            #pragma unroll
            for (int mi = 0; mi < 4; mi++)
                #pragma unroll
                for (int ni = 0; ni < 2; ni++)
                    acc[c][mi][ni] = __builtin_amdgcn_mfma_f32_16x16x32_bf16(av[mi][kc], bv[ni], acc[c][mi][ni], 0, 0, 0);
        }
    }

    #pragma unroll
    for (int ni = 0; ni < 2; ni++){
        int j = no + ni * 16 + cl;
        float bir = bih[j]       + bhh[j];
        float biz = bih[128 + j] + bhh[128 + j];
        float bin = bih[256 + j];
        float bhn = bhh[256 + j];
        #pragma unroll
        for (int mi = 0; mi < 4; mi++){
            long gm0 = baseM + mi * 16 + q * 4;
            #pragma unroll
            for (int reg = 0; reg < 4; reg++){
                long n_row = gm0 + reg;
                float gr = acc[0][mi][ni][reg] + bir;
                float gz = acc[1][mi][ni][reg] + biz;
                float gn = acc[2][mi][ni][reg] + bin;
                float r = fast_rcp(1.f + __expf(-gr));
                float z = fast_rcp(1.f + __expf(-gz));
                float ex = __expf(2.f * (gn + r * bhn));
                float nn = (ex - 1.f) * fast_rcp(ex + 1.f);
                float v = (1.f - z) * nn;
                if (n_row < Mreal){
                    if (outF32) ((float*)out)[n_row * 128 + j] = v;
                    else ((unsigned short*)out)[n_row * 128 + j] = f2b(v);
                }
            }
        }
    }
}

// ---------- per-edge-slot weights (padded slots -> 0) ----------
__global__ void edge_w(const int* __restrict__ esrc, const int* __restrict__ edst,
                       const float* __restrict__ el, const float* __restrict__ er,
                       float* __restrict__ wgtT){
    int p = blockIdx.x * 256 + threadIdx.x;
    int dn = edst[p];
    if (dn < 0){
        wgtT[0 * WSTRIDE_P + p] = 0.f;
        wgtT[1 * WSTRIDE_P + p] = 0.f;
        wgtT[2 * WSTRIDE_P + p] = 0.f;
        wgtT[3 * WSTRIDE_P + p] = 0.f;
        return;
    }
    int sn = esrc[p];
    float4 l = *(const float4*)(el + (size_t)sn * 4);
    float4 r = *(const float4*)(er + (size_t)dn * 4);
    float e;
    e = l.x + r.x; e = (e > 0.f) ? e : 0.2f * e; wgtT[0 * WSTRIDE_P + p] = __expf(e);
    e = l.y + r.y; e = (e > 0.f) ? e : 0.2f * e; wgtT[1 * WSTRIDE_P + p] = __expf(e);
    e = l.z + r.z; e = (e > 0.f) ? e : 0.2f * e; wgtT[2 * WSTRIDE_P + p] = __expf(e);
    e = l.w + r.w; e = (e > 0.f) ? e : 0.2f * e; wgtT[3 * WSTRIDE_P + p] = __expf(e);
}

// ---------- per-dst aggregation: padded-CSR, mask-free 8-edge groups, depth-2 pipeline -----
// One wave per node; lane covers dims (2*lane, 2*lane+1); head = lane>>4.
// h-row + bias hoisted above the loop (overlap the epilogue's HBM miss with the pipeline).
__global__ __launch_bounds__(256) void aggregate(
        const int* __restrict__ rowptr, const int* __restrict__ esrc,
        const float* __restrict__ wgtT,
        const unsigned short* __restrict__ feat, const float* __restrict__ bias,
        unsigned short* __restrict__ h)
{
    int wid = threadIdx.x >> 6, lane = threadIdx.x & 63;
    int n = blockIdx.x * 4 + wid;
    int hh = lane >> 4;
    int d0 = lane * 2;
    unsigned doff = (unsigned)(d0 * 2);           // byte offset inside a feat row
    int beg = rowptr[n], end = rowptr[n + 1];
    // hoisted epilogue inputs
    unsigned hv = *(const unsigned*)(h + (size_t)n * 128 + d0);
    float bias0 = bias[d0], bias1 = bias[d0 + 1];

    float s = 0.f, a0 = 0.f, a1 = 0.f;
    const char* fbc = (const char*)feat;
    const float* wp = wgtT + (size_t)hh * WSTRIDE_P + beg;
    const int*   ep = esrc + beg;

    if (beg < end){
        int4 sA = *(const int4*)(ep);
        int4 sB = *(const int4*)(ep + 4);
        float4 wA = make_float4(0.f,0.f,0.f,0.f), wB = wA;
        unsigned f0=0,f1=0,f2=0,f3=0,f4=0,f5=0,f6=0,f7=0;
        for (int p = beg; p < end; p += 8){
            // issue current group's data loads + next group's srcs
            float4 wcA = *(const float4*)(wp);
            float4 wcB = *(const float4*)(wp + 4);
            unsigned c0 = *(const unsigned*)(fbc + ((((unsigned)sA.x) << 8) + doff));
            unsigned c1 = *(const unsigned*)(fbc + ((((unsigned)sA.y) << 8) + doff));
            unsigned c2 = *(const unsigned*)(fbc + ((((unsigned)sA.z) << 8) + doff));
            unsigned c3 = *(const unsigned*)(fbc + ((((unsigned)sA.w) << 8) + doff));
            unsigned c4 = *(const unsigned*)(fbc + ((((unsigned)sB.x) << 8) + doff));
            unsigned c5 = *(const unsigned*)(fbc + ((((unsigned)sB.y) << 8) + doff));
            unsigned c6 = *(const unsigned*)(fbc + ((((unsigned)sB.z) << 8) + doff));
            unsigned c7 = *(const unsigned*)(fbc + ((((unsigned)sB.w) << 8) + doff));
            int4 nA = *(const int4*)(ep + 8);
            int4 nB = *(const int4*)(ep + 12);
            // consume previous group (zero-weight dummy on first iteration)
            s += ((wA.x + wA.y) + (wA.z + wA.w)) + ((wB.x + wB.y) + (wB.z + wB.w));
            a0 = fmaf(wA.x, bl(f0), fmaf(wA.y, bl(f1), fmaf(wA.z, bl(f2), fmaf(wA.w, bl(f3), a0))));
            a0 = fmaf(wB.x, bl(f4), fmaf(wB.y, bl(f5), fmaf(wB.z, bl(f6), fmaf(wB.w, bl(f7), a0))));
            a1 = fmaf(wA.x, bh(f0), fmaf(wA.y, bh(f1), fmaf(wA.z, bh(f2), fmaf(wA.w, bh(f3), a1))));
            a1 = fmaf(wB.x, bh(f4), fmaf(wB.y, bh(f5), fmaf(wB.z, bh(f6), fmaf(wB.w, bh(f7), a1))));
            wA = wcA; wB = wcB;
            f0 = c0; f1 = c1; f2 = c2; f3 = c3; f4 = c4; f5 = c5; f6 = c6; f7 = c7;
            sA = nA; sB = nB;
            wp += 8; ep += 8;
        }
        // final consume
        s += ((wA.x + wA.y) + (wA.z + wA.w)) + ((wB.x + wB.y) + (wB.z + wB.w));
        a0 = fmaf(wA.x, bl(f0), fmaf(wA.y, bl(f1), fmaf(wA.z, bl(f2), fmaf(wA.w, bl(f3), a0))));
        a0 = fmaf(wB.x, bl(f4), fmaf(wB.y, bl(f5), fmaf(wB.z, bl(f6), fmaf(wB.w, bl(f7), a0))));
        a1 = fmaf(wA.x, bh(f0), fmaf(wA.y, bh(f1), fmaf(wA.z, bh(f2), fmaf(wA.w, bh(f3), a1))));
        a1 = fmaf(wB.x, bh(f4), fmaf(wB.y, bh(f5), fmaf(wB.z, bh(f6), fmaf(wB.w, bh(f7), a1))));
    }
    float inv = (s > 0.f) ? fast_rcp(s) : 0.f;
    float x0 = a0 * inv + bl(hv) + bias0;
    float x1 = a1 * inv + bh(hv) + bias1;
    x0 = (x0 > 0.f) ? x0 : expm1f(x0);              // elu
    x1 = (x1 > 0.f) ? x1 : expm1f(x1);
    unsigned outv = (unsigned)f2b(x0) | ((unsigned)f2b(x1) << 16);
    *(unsigned*)(h + (size_t)n * 128 + d0) = outv;
}

extern "C" void kernel_launch(void* const* d_in, const int* in_sizes, int n_in,
                              void* d_out, int out_size, void* d_ws, size_t ws_size,
                              hipStream_t stream) {
    const float* node_feats = (const float*)d_in[0];
    const int*   srcp       = (const int*)d_in[1];
    const int*   dstp       = (const int*)d_in[2];
    const float* proj_W     = (const float*)d_in[3];
    const float* proj_b     = (const float*)d_in[4];
    const float* fc_W       = (const float*)d_in[5];
    const float* attn_l     = (const float*)d_in[6];
    const float* attn_r     = (const float*)d_in[7];
    const float* conv_bias  = (const float*)d_in[8];
    const float* gru_Wih    = (const float*)d_in[9];
    // d_in[10] gru_Whh unused (h0 == 0)
    const float* gru_bih    = (const float*)d_in[11];
    const float* gru_bhh    = (const float*)d_in[12];
    float* outp = (float*)d_out;

    char* ws = (char*)d_ws;
    size_t off = 0;
    auto carve = [&](size_t bytes) -> char* {
        char* p = ws + off;
        off += (bytes + 255) & ~(size_t)255;
        return p;
    };
    int*            deg    = (int*)carve((size_t)NNODES * 4);
    int*            rowptr = (int*)carve((size_t)(NNODES + 1) * 4);
    int*            cur    = (int*)carve((size_t)NNODES * 4);
    int*            esrc   = (int*)carve((size_t)(PADCAP + 32) * 4);
    int*            edst   = (int*)carve((size_t)PADCAP * 4);
    float*          el     = (float*)carve((size_t)NNODES * 4 * 4);
    float*          er     = (float*)carve((size_t)NNODES * 4 * 4);
    float*          wgtT   = (float*)carve((size_t)4 * WSTRIDE_P * 4);
    unsigned short* projWT = (unsigned short*)carve(16384 * 2);
    unsigned short* fcWT   = (unsigned short*)carve(3 * 16384 * 2);
    unsigned short* gruWb  = (unsigned short*)carve(49152 * 2);
    unsigned short* nf     = (unsigned short*)carve((size_t)NNODES * 128 * 2);
    unsigned short* h      = (unsigned short*)carve((size_t)M2PAD * 128 * 2);
    unsigned short* feat   = (unsigned short*)carve((size_t)M2PAD * 128 * 2);
    (void)ws_size; (void)in_sizes; (void)n_in; (void)out_size;

    // prep: zero deg + esrc (pad slots must gather node 0), edst = -1 (pad sentinel)
    hipMemsetAsync(deg, 0, (size_t)NNODES * 4, stream);
    hipMemsetAsync(esrc, 0, (size_t)(PADCAP + 32) * 4, stream);
    hipMemsetAsync(edst, 0xFF, (size_t)PADCAP * 4, stream);
    prep_all<<<7948, 256, 0, stream>>>(node_feats, proj_W, fc_W, gru_Wih, dstp,
                                       nf, projWT, fcWT, gruWb, deg);
    scan_kernel<<<1, 1024, 0, stream>>>(deg, rowptr, cur, NNODES);
    fill_kernel<<<NEDGES / 256, 256, 0, stream>>>(srcp, dstp, cur, esrc, edst);

    // input projection: h = node_feats @ proj_W + proj_b   (bf16 out)
    gemm_t<64><<<dim3(625, 1), 256, 0, stream>>>(nf, projWT, proj_b, h, NNODES, 128, 0,
                                                 nullptr, nullptr, nullptr, nullptr);

    // 3 GAT layers
    for (int l = 0; l < 3; l++){
        gemm_t<64><<<dim3(625, 1), 256, 0, stream>>>(h, fcWT + l * 16384, nullptr, feat, NNODES, 128, 0,
                                                     attn_l + l * 128, attn_r + l * 128, el, er);
        edge_w<<<PADCAP / 256, 256, 0, stream>>>(esrc, edst, el, er, wgtT);
        aggregate<<<NNODES / 4, 256, 0, stream>>>(rowptr, esrc, wgtT, feat, conv_bias + l * 128, h);
    }

    // 2 fused GRU steps
    gru_fused<<<625, 256, 0, stream>>>(h, gruWb, gru_bih, gru_bhh, h, NNODES, 0);
    gru_fused<<<625, 256, 0, stream>>>(h, gruWb, gru_bih, gru_bhh, outp, NNODES, 1);
}

// Round 10
// 365.865 us; speedup vs baseline: 1.1677x; 1.1677x over previous
//
#include <hip/hip_runtime.h>
#include <hip/hip_bf16.h>

#define NNODES 40000
#define NEDGES 640000
#define M2PAD  40064
#define HID    128
#define PADCAP 920064                 // >= NEDGES + 7*NNODES, multiple of 256
#define WSTRIDE_P (PADCAP + 16)       // wgtT plane stride (floats)

typedef __attribute__((ext_vector_type(8))) short bf16x8;
typedef __attribute__((ext_vector_type(4))) float f32x4;

__device__ __forceinline__ float bl(unsigned u){ return __uint_as_float(u << 16); }
__device__ __forceinline__ float bh(unsigned u){ return __uint_as_float(u & 0xFFFF0000u); }
__device__ __forceinline__ unsigned short f2b(float f){
    unsigned u = __float_as_uint(f);
    u = (u + 0x7FFFu + ((u >> 16) & 1u)) >> 16;   // round-to-nearest-even
    return (unsigned short)u;
}
__device__ __forceinline__ float fast_rcp(float x){ return __builtin_amdgcn_rcpf(x); }

__device__ __forceinline__ void g2l16(const void* g, void* l){
    __builtin_amdgcn_global_load_lds(
        (const __attribute__((address_space(1))) unsigned int*)g,
        (__attribute__((address_space(3))) unsigned int*)l, 16, 0, 0);
}

// ---------- prep: nf convert (0..4999) + transpose (5000..5255) + gru cvt (5256..5447)
//            + degree count (5448..7947) ----------
__global__ void prep_all(const float* __restrict__ node_feats,
                         const float* __restrict__ proj_W, const float* __restrict__ fc_W,
                         const float* __restrict__ gru_Wih, const int* __restrict__ dstp,
                         unsigned short* __restrict__ nf,
                         unsigned short* __restrict__ projWT, unsigned short* __restrict__ fcWT,
                         unsigned short* __restrict__ gruWb, int* __restrict__ deg){
    int b = blockIdx.x;
    if (b < 5000){
        int gid = b * 256 + threadIdx.x;     // 4 elems each
        float4 v = ((const float4*)node_feats)[gid];
        ushort4 o;
        o.x = f2b(v.x); o.y = f2b(v.y); o.z = f2b(v.z); o.w = f2b(v.w);
        ((ushort4*)nf)[gid] = o;
    } else if (b < 5256){
        int t = b - 5000;
        int c = t >> 6;                      // matrix 0..3
        int idx = (t & 63) * 256 + threadIdx.x;   // coalesced read
        const float* in   = (c == 0) ? proj_W : fc_W + (size_t)(c - 1) * 16384;
        unsigned short* o = (c == 0) ? projWT : fcWT + (size_t)(c - 1) * 16384;
        int k = idx >> 7, n = idx & 127;
        o[n * 128 + k] = f2b(in[idx]);       // scattered 2B write
    } else if (b < 5448){
        int idx = (b - 5256) * 256 + threadIdx.x;
        gruWb[idx] = f2b(gru_Wih[idx]);      // (384,128) already B^T layout
    } else {
        int e = (b - 5448) * 256 + threadIdx.x;
        atomicAdd(&deg[dstp[e]], 1);
    }
}

// ---------- CSR scan (rows padded to multiple of 8), 4 nodes/thread via int4 ----------
__global__ __launch_bounds__(1024) void scan_kernel(const int* __restrict__ deg,
        int* __restrict__ rowptr, int* __restrict__ cur, int Nn4){
    __shared__ int wsum[17];
    __shared__ int carry;
    int t = threadIdx.x, lane = t & 63, wid = t >> 6;
    if (t == 0) carry = 0;
    __syncthreads();
    for (int base = 0; base < Nn4; base += 1024){
        int i4 = base + t;
        int4 dg = (i4 < Nn4) ? ((const int4*)deg)[i4] : make_int4(0, 0, 0, 0);
        int p0 = (dg.x + 7) & ~7, p1 = (dg.y + 7) & ~7;
        int p2 = (dg.z + 7) & ~7, p3 = (dg.w + 7) & ~7;
        int v = p0 + p1 + p2 + p3;
        int x = v;
        #pragma unroll
        for (int d = 1; d < 64; d <<= 1){
            int y = __shfl_up(x, d, 64);
            if (lane >= d) x += y;
        }
        if (lane == 63) wsum[wid] = x;
        __syncthreads();
        if (wid == 0){
            int vv = (lane < 16) ? wsum[lane] : 0;
            int xx = vv;
            #pragma unroll
            for (int d = 1; d < 16; d <<= 1){
                int y = __shfl_up(xx, d, 64);
                if (lane >= d) xx += y;
            }
            if (lane < 16) wsum[lane] = xx - vv;      // exclusive
            if (lane == 15) wsum[16] = xx;            // total
        }
        __syncthreads();
        int excl = carry + wsum[wid] + (x - v);
        if (i4 < Nn4){
            int4 o = make_int4(excl, excl + p0, excl + p0 + p1, excl + p0 + p1 + p2);
            ((int4*)rowptr)[i4] = o;
            ((int4*)cur)[i4]    = o;
        }
        __syncthreads();
        if (t == 0) carry += wsum[16];
        __syncthreads();
    }
    if (t == 0) rowptr[Nn4 * 4] = carry;
}

__global__ void fill_kernel(const int* __restrict__ src, const int* __restrict__ dst,
                            int* __restrict__ cur, int* __restrict__ esrc,
                            int* __restrict__ edst){
    int e = blockIdx.x * 256 + threadIdx.x;
    int d = dst[e];
    int pos = atomicAdd(&cur[d], 1);
    esrc[pos] = src[e];
    edst[pos] = d;
}

// ---------- GEMM: C[M x Nout] = A[M x 128](bf16) * BT[Nout x 128]^T (+bias fp32) ----------
// MT=64: 4 waves, each 64 rows x 32 cols. Optional fused el/er (wave w == head w).
template<int MT>
__global__ __launch_bounds__(256) void gemm_t(
        const unsigned short* __restrict__ A, const unsigned short* __restrict__ BT,
        const float* __restrict__ bias, void* __restrict__ C,
        int Mreal, int ldc, int outF32,
        const float* __restrict__ al, const float* __restrict__ ar,
        float* __restrict__ elp, float* __restrict__ erp)
{
    __shared__ unsigned char lds[MT * 256 + 32768];
    unsigned char* ldsA = lds;
    unsigned char* ldsB = lds + MT * 256;
    int w = threadIdx.x >> 6, lane = threadIdx.x & 63;
    int rsub = lane >> 4, c16 = lane & 15;
    long baseM = (long)blockIdx.x * MT;
    long baseN = (long)blockIdx.y * 128;

    #pragma unroll
    for (int i = 0; i < MT / 16; i++){
        int chunk = w * (MT / 16) + i;
        int r = chunk * 4 + rsub;
        int cg = c16 ^ (r & 15);
        long ar_ = baseM + r; if (ar_ >= Mreal) ar_ = Mreal - 1;
        g2l16((const unsigned char*)A + ar_ * 256 + cg * 16, ldsA + chunk * 1024);
    }
    #pragma unroll
    for (int i = 0; i < 8; i++){
        int chunk = w * 8 + i;
        int r = chunk * 4 + rsub;
        int cg = c16 ^ (r & 15);
        long br = baseN + r;
        g2l16((const unsigned char*)BT + br * 256 + cg * 16, ldsB + chunk * 1024);
    }
    __syncthreads();

    constexpr int MI = 4;
    constexpr int NI = (MT == 128) ? 4 : 2;
    int mo = (MT == 128) ? (w & 1) * 64 : 0;
    int no = (MT == 128) ? (w >> 1) * 64 : w * 32;
    int q = lane >> 4, cl = lane & 15;
    f32x4 acc[MI][NI];
    #pragma unroll
    for (int i = 0; i < MI; i++)
        #pragma unroll
        for (int j = 0; j < NI; j++) acc[i][j] = (f32x4){0.f, 0.f, 0.f, 0.f};

    #pragma unroll
    for (int kc = 0; kc < 4; kc++){
        bf16x8 av[MI], bv[NI];
        #pragma unroll
        for (int mi = 0; mi < MI; mi++){
            int row = mo + mi * 16 + cl;
            int cs = (kc * 4 + q) ^ (row & 15);
            av[mi] = *(const bf16x8*)(ldsA + row * 256 + cs * 16);
        }
        #pragma unroll
        for (int ni = 0; ni < NI; ni++){
            int row = no + ni * 16 + cl;
            int cs = (kc * 4 + q) ^ (row & 15);
            bv[ni] = *(const bf16x8*)(ldsB + row * 256 + cs * 16);
        }
        #pragma unroll
        for (int mi = 0; mi < MI; mi++)
            #pragma unroll
            for (int ni = 0; ni < NI; ni++)
                acc[mi][ni] = __builtin_amdgcn_mfma_f32_16x16x32_bf16(av[mi], bv[ni], acc[mi][ni], 0, 0, 0);
    }

    // epilogue: C/D layout col=lane&15, row=(lane>>4)*4+reg
    #pragma unroll
    for (int mi = 0; mi < MI; mi++){
        #pragma unroll
        for (int ni = 0; ni < NI; ni++){
            int gn = (int)baseN + no + ni * 16 + cl;
            float bvf = bias ? bias[gn] : 0.f;
            long gm0 = baseM + mo + mi * 16 + q * 4;
            #pragma unroll
            for (int reg = 0; reg < 4; reg++){
                float v = acc[mi][ni][reg] + bvf;
                long gm = gm0 + reg;
                if (gm < Mreal){
                    if (outF32) ((float*)C)[gm * ldc + gn] = v;
                    else ((unsigned short*)C)[gm * ldc + gn] = f2b(v);
                }
            }
        }
    }

    // fused el/er: wave w == head w (cols w*32..w*32+31). 16-lane xor reduction over cl.
    if (NI == 2 && al){
        float al_lo = al[no + cl], al_hi = al[no + 16 + cl];
        float ar_lo = ar[no + cl], ar_hi = ar[no + 16 + cl];
        #pragma unroll
        for (int mi = 0; mi < MI; mi++){
            #pragma unroll
            for (int reg = 0; reg < 4; reg++){
                float pl = acc[mi][0][reg] * al_lo + acc[mi][1][reg] * al_hi;
                float pr = acc[mi][0][reg] * ar_lo + acc[mi][1][reg] * ar_hi;
                #pragma unroll
                for (int msk = 8; msk; msk >>= 1){
                    pl += __shfl_xor(pl, msk, 64);
                    pr += __shfl_xor(pr, msk, 64);
                }
                long gm = baseM + mi * 16 + q * 4 + reg;
                if (cl == 0 && gm < Mreal){
                    elp[gm * 4 + w] = pl;
                    erp[gm * 4 + w] = pr;
                }
            }
        }
    }
}

// ---------- fused GRU (round-6/8 version: A staged in LDS) ----------
__global__ __launch_bounds__(256) void gru_fused(
        const unsigned short* __restrict__ A, const unsigned short* __restrict__ BT,
        const float* __restrict__ bih, const float* __restrict__ bhh,
        void* __restrict__ out, int Mreal, int outF32)
{
    __shared__ unsigned char ldsA[16384];
    __shared__ unsigned char ldsB[32768];
    int w = threadIdx.x >> 6, lane = threadIdx.x & 63;
    int rsub = lane >> 4, c16 = lane & 15;
    long baseM = (long)blockIdx.x * 64;

    #pragma unroll
    for (int i = 0; i < 4; i++){
        int chunk = w * 4 + i;
        int r = chunk * 4 + rsub;
        int cg = c16 ^ (r & 15);
        long ar = baseM + r; if (ar >= Mreal) ar = Mreal - 1;
        g2l16((const unsigned char*)A + ar * 256 + cg * 16, ldsA + chunk * 1024);
    }

    int no = w * 32;
    int q = lane >> 4, cl = lane & 15;
    f32x4 acc[3][4][2];
    #pragma unroll
    for (int c = 0; c < 3; c++)
        #pragma unroll
        for (int i = 0; i < 4; i++)
            #pragma unroll
            for (int j = 0; j < 2; j++) acc[c][i][j] = (f32x4){0.f, 0.f, 0.f, 0.f};

    for (int c = 0; c < 3; c++){
        if (c) __syncthreads();
        #pragma unroll
        for (int i = 0; i < 8; i++){
            int chunk = w * 8 + i;
            int r = chunk * 4 + rsub;
            int cg = c16 ^ (r & 15);
            long br = c * 128 + r;
            g2l16((const unsigned char*)BT + br * 256 + cg * 16, ldsB + chunk * 1024);
        }
        __syncthreads();
        #pragma unroll
        for (int kc = 0; kc < 4; kc++){
            bf16x8 av[4], bv[2];
            #pragma unroll
            for (int mi = 0; mi < 4; mi++){
                int row = mi * 16 + cl;
                int cs = (kc * 4 + q) ^ (row & 15);
                av[mi] = *(const bf16x8*)(ldsA + row * 256 + cs * 16);
            }
            #pragma unroll
            for (int ni = 0; ni < 2; ni++){
                int row = no + ni * 16 + cl;
                int cs = (kc * 4 + q) ^ (row & 15);
                bv[ni] = *(const bf16x8*)(ldsB + row * 256 + cs * 16);
            }
            #pragma unroll
            for (int mi = 0; mi < 4; mi++)
                #pragma unroll
                for (int ni = 0; ni < 2; ni++)
                    acc[c][mi][ni] = __builtin_amdgcn_mfma_f32_16x16x32_bf16(av[mi], bv[ni], acc[c][mi][ni], 0, 0, 0);
        }
    }

    #pragma unroll
    for (int ni = 0; ni < 2; ni++){
        int j = no + ni * 16 + cl;
        float bir = bih[j]       + bhh[j];
        float biz = bih[128 + j] + bhh[128 + j];
        float bin = bih[256 + j];
        float bhn = bhh[256 + j];
        #pragma unroll
        for (int mi = 0; mi < 4; mi++){
            long gm0 = baseM + mi * 16 + q * 4;
            #pragma unroll
            for (int reg = 0; reg < 4; reg++){
                long n_row = gm0 + reg;
                float gr = acc[0][mi][ni][reg] + bir;
                float gz = acc[1][mi][ni][reg] + biz;
                float gn = acc[2][mi][ni][reg] + bin;
                float r = fast_rcp(1.f + __expf(-gr));
                float z = fast_rcp(1.f + __expf(-gz));
                float ex = __expf(2.f * (gn + r * bhn));
                float nn = (ex - 1.f) * fast_rcp(ex + 1.f);
                float v = (1.f - z) * nn;
                if (n_row < Mreal){
                    if (outF32) ((float*)out)[n_row * 128 + j] = v;
                    else ((unsigned short*)out)[n_row * 128 + j] = f2b(v);
                }
            }
        }
    }
}

// ---------- per-edge-slot weights (padded slots -> 0) ----------
__global__ void edge_w(const int* __restrict__ esrc, const int* __restrict__ edst,
                       const float* __restrict__ el, const float* __restrict__ er,
                       float* __restrict__ wgtT){
    int p = blockIdx.x * 256 + threadIdx.x;
    int dn = edst[p];
    if (dn < 0){
        wgtT[0 * WSTRIDE_P + p] = 0.f;
        wgtT[1 * WSTRIDE_P + p] = 0.f;
        wgtT[2 * WSTRIDE_P + p] = 0.f;
        wgtT[3 * WSTRIDE_P + p] = 0.f;
        return;
    }
    int sn = esrc[p];
    float4 l = *(const float4*)(el + (size_t)sn * 4);
    float4 r = *(const float4*)(er + (size_t)dn * 4);
    float e;
    e = l.x + r.x; e = (e > 0.f) ? e : 0.2f * e; wgtT[0 * WSTRIDE_P + p] = __expf(e);
    e = l.y + r.y; e = (e > 0.f) ? e : 0.2f * e; wgtT[1 * WSTRIDE_P + p] = __expf(e);
    e = l.z + r.z; e = (e > 0.f) ? e : 0.2f * e; wgtT[2 * WSTRIDE_P + p] = __expf(e);
    e = l.w + r.w; e = (e > 0.f) ? e : 0.2f * e; wgtT[3 * WSTRIDE_P + p] = __expf(e);
}

// ---------- per-dst aggregation: padded-CSR, mask-free 8-edge groups, depth-2 pipeline -----
// One wave per node; lane covers dims (2*lane, 2*lane+1); head = lane>>4.
__global__ __launch_bounds__(256) void aggregate(
        const int* __restrict__ rowptr, const int* __restrict__ esrc,
        const float* __restrict__ wgtT,
        const unsigned short* __restrict__ feat, const float* __restrict__ bias,
        unsigned short* __restrict__ h)
{
    int wid = threadIdx.x >> 6, lane = threadIdx.x & 63;
    int n = blockIdx.x * 4 + wid;
    int hh = lane >> 4;
    int d0 = lane * 2;
    unsigned doff = (unsigned)(d0 * 2);           // byte offset inside a feat row
    int beg = rowptr[n], end = rowptr[n + 1];
    float s = 0.f, a0 = 0.f, a1 = 0.f;
    const char* fbc = (const char*)feat;
    const float* wp = wgtT + (size_t)hh * WSTRIDE_P + beg;
    const int*   ep = esrc + beg;

    if (beg < end){
        int4 sA = *(const int4*)(ep);
        int4 sB = *(const int4*)(ep + 4);
        float4 wA = make_float4(0.f,0.f,0.f,0.f), wB = wA;
        unsigned f0=0,f1=0,f2=0,f3=0,f4=0,f5=0,f6=0,f7=0;
        for (int p = beg; p < end; p += 8){
            // issue current group's data loads + next group's srcs
            float4 wcA = *(const float4*)(wp);
            float4 wcB = *(const float4*)(wp + 4);
            unsigned c0 = *(const unsigned*)(fbc + ((((unsigned)sA.x) << 8) + doff));
            unsigned c1 = *(const unsigned*)(fbc + ((((unsigned)sA.y) << 8) + doff));
            unsigned c2 = *(const unsigned*)(fbc + ((((unsigned)sA.z) << 8) + doff));
            unsigned c3 = *(const unsigned*)(fbc + ((((unsigned)sA.w) << 8) + doff));
            unsigned c4 = *(const unsigned*)(fbc + ((((unsigned)sB.x) << 8) + doff));
            unsigned c5 = *(const unsigned*)(fbc + ((((unsigned)sB.y) << 8) + doff));
            unsigned c6 = *(const unsigned*)(fbc + ((((unsigned)sB.z) << 8) + doff));
            unsigned c7 = *(const unsigned*)(fbc + ((((unsigned)sB.w) << 8) + doff));
            int4 nA = *(const int4*)(ep + 8);
            int4 nB = *(const int4*)(ep + 12);
            // consume previous group (zero-weight dummy on first iteration)
            s += ((wA.x + wA.y) + (wA.z + wA.w)) + ((wB.x + wB.y) + (wB.z + wB.w));
            a0 = fmaf(wA.x, bl(f0), fmaf(wA.y, bl(f1), fmaf(wA.z, bl(f2), fmaf(wA.w, bl(f3), a0))));
            a0 = fmaf(wB.x, bl(f4), fmaf(wB.y, bl(f5), fmaf(wB.z, bl(f6), fmaf(wB.w, bl(f7), a0))));
            a1 = fmaf(wA.x, bh(f0), fmaf(wA.y, bh(f1), fmaf(wA.z, bh(f2), fmaf(wA.w, bh(f3), a1))));
            a1 = fmaf(wB.x, bh(f4), fmaf(wB.y, bh(f5), fmaf(wB.z, bh(f6), fmaf(wB.w, bh(f7), a1))));
            wA = wcA; wB = wcB;
            f0 = c0; f1 = c1; f2 = c2; f3 = c3; f4 = c4; f5 = c5; f6 = c6; f7 = c7;
            sA = nA; sB = nB;
            wp += 8; ep += 8;
        }
        // final consume
        s += ((wA.x + wA.y) + (wA.z + wA.w)) + ((wB.x + wB.y) + (wB.z + wB.w));
        a0 = fmaf(wA.x, bl(f0), fmaf(wA.y, bl(f1), fmaf(wA.z, bl(f2), fmaf(wA.w, bl(f3), a0))));
        a0 = fmaf(wB.x, bl(f4), fmaf(wB.y, bl(f5), fmaf(wB.z, bl(f6), fmaf(wB.w, bl(f7), a0))));
        a1 = fmaf(wA.x, bh(f0), fmaf(wA.y, bh(f1), fmaf(wA.z, bh(f2), fmaf(wA.w, bh(f3), a1))));
        a1 = fmaf(wB.x, bh(f4), fmaf(wB.y, bh(f5), fmaf(wB.z, bh(f6), fmaf(wB.w, bh(f7), a1))));
    }
    float inv = (s > 0.f) ? fast_rcp(s) : 0.f;
    unsigned hv = *(const unsigned*)(h + (size_t)n * 128 + d0);
    float x0 = a0 * inv + bl(hv) + bias[d0];
    float x1 = a1 * inv + bh(hv) + bias[d0 + 1];
    x0 = (x0 > 0.f) ? x0 : expm1f(x0);              // elu
    x1 = (x1 > 0.f) ? x1 : expm1f(x1);
    unsigned outv = (unsigned)f2b(x0) | ((unsigned)f2b(x1) << 16);
    *(unsigned*)(h + (size_t)n * 128 + d0) = outv;
}

extern "C" void kernel_launch(void* const* d_in, const int* in_sizes, int n_in,
                              void* d_out, int out_size, void* d_ws, size_t ws_size,
                              hipStream_t stream) {
    const float* node_feats = (const float*)d_in[0];
    const int*   srcp       = (const int*)d_in[1];
    const int*   dstp       = (const int*)d_in[2];
    const float* proj_W     = (const float*)d_in[3];
    const float* proj_b     = (const float*)d_in[4];
    const float* fc_W       = (const float*)d_in[5];
    const float* attn_l     = (const float*)d_in[6];
    const float* attn_r     = (const float*)d_in[7];
    const float* conv_bias  = (const float*)d_in[8];
    const float* gru_Wih    = (const float*)d_in[9];
    // d_in[10] gru_Whh unused (h0 == 0)
    const float* gru_bih    = (const float*)d_in[11];
    const float* gru_bhh    = (const float*)d_in[12];
    float* outp = (float*)d_out;

    char* ws = (char*)d_ws;
    size_t off = 0;
    auto carve = [&](size_t bytes) -> char* {
        char* p = ws + off;
        off += (bytes + 255) & ~(size_t)255;
        return p;
    };
    int*            deg    = (int*)carve((size_t)NNODES * 4);
    int*            rowptr = (int*)carve((size_t)(NNODES + 1) * 4);
    int*            cur    = (int*)carve((size_t)NNODES * 4);
    int*            esrc   = (int*)carve((size_t)(PADCAP + 32) * 4);
    int*            edst   = (int*)carve((size_t)PADCAP * 4);
    float*          el     = (float*)carve((size_t)NNODES * 4 * 4);
    float*          er     = (float*)carve((size_t)NNODES * 4 * 4);
    float*          wgtT   = (float*)carve((size_t)4 * WSTRIDE_P * 4);
    unsigned short* projWT = (unsigned short*)carve(16384 * 2);
    unsigned short* fcWT   = (unsigned short*)carve(3 * 16384 * 2);
    unsigned short* gruWb  = (unsigned short*)carve(49152 * 2);
    unsigned short* nf     = (unsigned short*)carve((size_t)NNODES * 128 * 2);
    unsigned short* h      = (unsigned short*)carve((size_t)M2PAD * 128 * 2);
    unsigned short* feat   = (unsigned short*)carve((size_t)M2PAD * 128 * 2);
    (void)ws_size; (void)in_sizes; (void)n_in; (void)out_size;

    // prep: zero deg + esrc (pad slots must gather node 0), edst = -1 (pad sentinel)
    hipMemsetAsync(deg, 0, (size_t)NNODES * 4, stream);
    hipMemsetAsync(esrc, 0, (size_t)(PADCAP + 32) * 4, stream);
    hipMemsetAsync(edst, 0xFF, (size_t)PADCAP * 4, stream);
    prep_all<<<7948, 256, 0, stream>>>(node_feats, proj_W, fc_W, gru_Wih, dstp,
                                       nf, projWT, fcWT, gruWb, deg);
    scan_kernel<<<1, 1024, 0, stream>>>(deg, rowptr, cur, NNODES / 4);
    fill_kernel<<<NEDGES / 256, 256, 0, stream>>>(srcp, dstp, cur, esrc, edst);

    // input projection: h = node_feats @ proj_W + proj_b   (bf16 out)
    gemm_t<64><<<dim3(625, 1), 256, 0, stream>>>(nf, projWT, proj_b, h, NNODES, 128, 0,
                                                 nullptr, nullptr, nullptr, nullptr);

    // 3 GAT layers
    for (int l = 0; l < 3; l++){
        gemm_t<64><<<dim3(625, 1), 256, 0, stream>>>(h, fcWT + l * 16384, nullptr, feat, NNODES, 128, 0,
                                                     attn_l + l * 128, attn_r + l * 128, el, er);
        edge_w<<<PADCAP / 256, 256, 0, stream>>>(esrc, edst, el, er, wgtT);
        aggregate<<<NNODES / 4, 256, 0, stream>>>(rowptr, esrc, wgtT, feat, conv_bias + l * 128, h);
    }

    // 2 fused GRU steps
    gru_fused<<<625, 256, 0, stream>>>(h, gruWb, gru_bih, gru_bhh, h, NNODES, 0);
    gru_fused<<<625, 256, 0, stream>>>(h, gruWb, gru_bih, gru_bhh, outp, NNODES, 1);
}